// Round 5
// baseline (213.013 us; speedup 1.0000x reference)
//
#include <hip/hip_runtime.h>
#include <hip/hip_bf16.h>

#define BB 4
#define SS 2048
#define DIN 512
#define UU 64
#define WINR 32
#define LTOT 132064   // sum of per-anchor window lengths
#define GQ 16         // queries per attn block (8 waves x query-pair)
#define NWP 144       // max union key-window rows for GQ=16 (64+16+64)
#define KST 66        // ushort stride for K/V LDS rows (132 B -> conflict-free)

typedef __attribute__((ext_vector_type(8))) short short8;
typedef __attribute__((ext_vector_type(4))) float float4v;

static __device__ __forceinline__ ushort f2bf(float f) {
    union { __hip_bfloat16 h; ushort u; } c;
    c.h = __float2bfloat16(f);
    return c.u;
}
static __device__ __forceinline__ float bf2f(ushort u) {
    union { float f; uint v; } c;
    c.v = ((uint)u) << 16;
    return c.f;
}

// offsets[s] = sum_{t<s} (min(t+33,S) - max(t-32,0)), closed form (verified vs cumsum)
__device__ __forceinline__ int offs_of(int s) {
    int a = s < (SS - 33) ? s : (SS - 33);
    int m = (s - 33) > 0 ? (s - 33) : 0;
    return a * (a - 1) / 2 + 33 * a + (s - a) * SS - m * (m + 1) / 2;
}

// ---------------- Kernel 0: W (fp32, K-major [512][64]) -> Wt (bf16, N-major [3][64][512]) ----
__global__ __launch_bounds__(256) void prep_w(
    const float* __restrict__ Wq, const float* __restrict__ Wk, const float* __restrict__ Wv,
    ushort* __restrict__ Wt)
{
    __shared__ float T[64][65];
    const int mtx = blockIdx.x >> 3;   // 0..2
    const int kc  = blockIdx.x & 7;    // 0..7  (K chunk of 64)
    const float* W = (mtx == 0) ? Wq : ((mtx == 1) ? Wk : Wv);
    const int tid = threadIdx.x;
    for (int idx = tid; idx < 64 * 64; idx += 256) {
        const int k = idx >> 6, n = idx & 63;          // coalesced read over n
        T[n][k] = W[(size_t)(kc * 64 + k) * UU + n];
    }
    __syncthreads();
    for (int idx = tid; idx < 64 * 64; idx += 256) {
        const int n = idx >> 6, kl = idx & 63;
        Wt[(size_t)mtx * UU * DIN + (size_t)n * DIN + kc * 64 + kl] = f2bf(T[n][kl]);
    }
}

// ---------------- Kernel 1: QKV projection, MFMA 16x16x32, K-split across 4 waves ----------
// grid = 3*512 blocks x 256 threads. Block (mtx, rt): rows rt*16..+15, all 64 cols.
// Wave kq handles K range [kq*128, kq*128+128); partials reduced through LDS.
__global__ __launch_bounds__(256) void qkv_mfma(
    const float* __restrict__ query, const float* __restrict__ value,
    const ushort* __restrict__ Wt,
    const float* __restrict__ bq, const float* __restrict__ bk, const float* __restrict__ bv,
    float* __restrict__ Qs, ushort* __restrict__ Kf, ushort* __restrict__ Vf)
{
    __shared__ float red[4][16 * UU];   // 16 KB partials
    const int bid = blockIdx.x;
    const int mtx = bid >> 9;           // 0=Q 1=K 2=V
    const int rt  = bid & 511;
    const int tid = threadIdx.x;
    const int kq = tid >> 6;            // K-quarter
    const int lane = tid & 63;
    const int m16 = lane & 15, quad = lane >> 4;

    const float* X = (mtx == 0) ? query : value;
    const float* Xrow = X + (size_t)(rt * 16 + m16) * DIN + kq * 128 + quad * 8;
    const ushort* Wm = Wt + (size_t)mtx * UU * DIN + (size_t)m16 * DIN + kq * 128 + quad * 8;

    float4v acc[4];
#pragma unroll
    for (int nb = 0; nb < 4; ++nb) acc[nb] = (float4v){0.f, 0.f, 0.f, 0.f};

#pragma unroll
    for (int kk = 0; kk < 4; ++kk) {
        const float4 xa = *(const float4*)(Xrow + kk * 32);
        const float4 xb = *(const float4*)(Xrow + kk * 32 + 4);
        short8 a;
        a[0] = (short)f2bf(xa.x); a[1] = (short)f2bf(xa.y);
        a[2] = (short)f2bf(xa.z); a[3] = (short)f2bf(xa.w);
        a[4] = (short)f2bf(xb.x); a[5] = (short)f2bf(xb.y);
        a[6] = (short)f2bf(xb.z); a[7] = (short)f2bf(xb.w);
#pragma unroll
        for (int nb = 0; nb < 4; ++nb) {
            const short8 bfr = *(const short8*)(Wm + (size_t)nb * 16 * DIN + kk * 32);
            acc[nb] = __builtin_amdgcn_mfma_f32_16x16x32_bf16(a, bfr, acc[nb], 0, 0, 0);
        }
    }

    // C layout (16x16x32): col = lane&15 (within nb tile), row = quad*4 + reg
#pragma unroll
    for (int nb = 0; nb < 4; ++nb)
#pragma unroll
        for (int reg = 0; reg < 4; ++reg)
            red[kq][(quad * 4 + reg) * UU + nb * 16 + m16] = acc[nb][reg];
    __syncthreads();

    const float* bias = (mtx == 0) ? bq : ((mtx == 1) ? bk : bv);
#pragma unroll
    for (int i = 0; i < 4; ++i) {
        const int e = tid + 256 * i;
        const int col = e & 63, row = e >> 6;
        float s = red[0][e] + red[1][e] + red[2][e] + red[3][e] + bias[col];
        const size_t gi = (size_t)(rt * 16 + row) * UU + col;
        if (mtx == 0)      Qs[gi] = s * 0.125f;    // 1/sqrt(UNITS)
        else if (mtx == 1) Kf[gi] = f2bf(s);
        else               Vf[gi] = f2bf(s);
    }
}

// ---------------- Kernel 2: banded exp-scores + paired sliding-window weighted sums --------
// 512 threads (8 waves) per block; GQ=16 queries. Wave w owns query pair (q0+2w, q0+2w+1)
// and slides the full anchor range once: V-row adds/removes are anchor- (not query-)
// dependent, so one slide serves both queries. No softmax-max pass (|score| small).
__global__ __launch_bounds__(512) void attn_kernel(
    const float* __restrict__ Qs, const ushort* __restrict__ Kf,
    const ushort* __restrict__ Vf, float* __restrict__ out)
{
    __shared__ ushort Kl[NWP * KST];     // 19,008 B
    __shared__ ushort Vl[NWP * KST];     // 19,008 B
    __shared__ float  ev[GQ][NWP];       //  9,216 B
    __shared__ float  qr[GQ][UU];        //  4,096 B   (total 51.3 KB < 64 KB)

    const int blk = blockIdx.x;
    const int b = blk >> 7;              // 128 blocks per batch
    const int q0 = (blk & 127) << 4;
    const int tid = threadIdx.x;

    const int j0 = max(q0 - 2 * WINR, 0);
    const int j1 = min(q0 + GQ - 1 + 2 * WINR + 1, SS);
    const int nw = j1 - j0;

    for (int idx = tid; idx < GQ * UU; idx += 512)
        qr[idx >> 6][idx & 63] = Qs[((size_t)b * SS + q0) * UU + idx];

    const uint* Kg = (const uint*)(Kf + ((size_t)b * SS + j0) * UU);
    const uint* Vg = (const uint*)(Vf + ((size_t)b * SS + j0) * UU);
    for (int idx = tid; idx < nw * 32; idx += 512) {
        const int j = idx >> 5, d2 = idx & 31;
        ((uint*)(Kl + j * KST))[d2] = Kg[idx];
        ((uint*)(Vl + j * KST))[d2] = Vg[idx];
    }
    __syncthreads();

    // exp-scores for all 16 queries over the union band (Q pre-scaled by 1/8)
    for (int item = tid; item < GQ * NWP; item += 512) {
        const int g = item / NWP, jj = item - g * NWP;
        float e = 0.f;
        if (jj < nw) {
            const uint* kr = (const uint*)(Kl + jj * KST);
            const float* q = qr[g];
            float dot = 0.f;
#pragma unroll
            for (int p = 0; p < UU / 2; ++p) {           // kr[p],kr[p+1] & q pairs fuse to ds_read2_b32
                const uint kp = kr[p];
                dot = fmaf(q[2 * p],     bf2f((ushort)kp),         dot);
                dot = fmaf(q[2 * p + 1], bf2f((ushort)(kp >> 16)), dot);
            }
            e = __expf(dot);
        }
        ev[g][jj] = e;
    }
    __syncthreads();

    // paired sliding-window accumulation: wave w -> queries qA=q0+2w, qB=qA+1
    const int w = tid >> 6, lane = tid & 63;
    const int qA = q0 + 2 * w, qB = qA + 1;
    const int sA = max(qA - WINR, 0);
    const int sB = min(qB + WINR, SS - 1);
    int st = max(sA - WINR, 0);
    int en = min(sA + WINR + 1, SS);
    const float* eA = ev[2 * w];
    const float* eB = ev[2 * w + 1];

    float accA = 0.f, denA = 0.f, accB = 0.f, denB = 0.f;
    for (int j = st; j < en; ++j) {
        const float v = bf2f(Vl[(j - j0) * KST + lane]);
        const float a = eA[j - j0], bw = eB[j - j0];
        accA = fmaf(a, v, accA);  denA += a;
        accB = fmaf(bw, v, accB); denB += bw;
    }
    int off = offs_of(sA);
    float* outb = out + (size_t)b * LTOT * UU;
    for (int s = sA;; ++s) {
        if (s <= qA + WINR)   // qA is a member of anchor s's window
            outb[(size_t)(off + qA - st) * UU + lane] = accA * __builtin_amdgcn_rcpf(denA);
        if (s >= qB - WINR)   // qB membership
            outb[(size_t)(off + qB - st) * UU + lane] = accB * __builtin_amdgcn_rcpf(denB);
        if (s == sB) break;
        off += en - st;
        if (en < SS) {                   // window end grows: add key j = en
            const float v = bf2f(Vl[(en - j0) * KST + lane]);
            const float a = eA[en - j0], bw = eB[en - j0];
            accA = fmaf(a, v, accA);  denA += a;
            accB = fmaf(bw, v, accB); denB += bw;
            ++en;
        }
        if (s + 1 > WINR) {              // window start grows: remove key j = st
            const float v = bf2f(Vl[(st - j0) * KST + lane]);
            const float a = eA[st - j0], bw = eB[st - j0];
            accA = fmaf(-a, v, accA);  denA -= a;
            accB = fmaf(-bw, v, accB); denB -= bw;
            ++st;
        }
    }
}

extern "C" void kernel_launch(void* const* d_in, const int* in_sizes, int n_in,
                              void* d_out, int out_size, void* d_ws, size_t ws_size,
                              hipStream_t stream) {
    const float* query = (const float*)d_in[0];
    const float* value = (const float*)d_in[1];
    const float* Wq = (const float*)d_in[2];
    const float* bq = (const float*)d_in[3];
    const float* Wk = (const float*)d_in[4];
    const float* bk = (const float*)d_in[5];
    const float* Wv = (const float*)d_in[6];
    const float* bv = (const float*)d_in[7];
    float* out = (float*)d_out;

    // ws: Qs fp32 (2 MB) + Kf bf16 (1 MB) + Vf bf16 (1 MB)
    float* Qs = (float*)d_ws;
    ushort* Kf = (ushort*)(Qs + (size_t)BB * SS * UU);
    ushort* Vf = Kf + (size_t)BB * SS * UU;
    // Wt (bf16 [3][64][512], 192 KB) in the TAIL of d_out: prep_w writes, qkv_mfma reads,
    // attn_kernel then overwrites every output row (stream-ordered, 16B-aligned).
    ushort* Wt = (ushort*)((float*)d_out + (size_t)out_size) - (size_t)3 * UU * DIN;

    prep_w<<<24, 256, 0, stream>>>(Wq, Wk, Wv, Wt);
    qkv_mfma<<<3 * 512, 256, 0, stream>>>(query, value, Wt, bq, bk, bv, Qs, Kf, Vf);
    attn_kernel<<<BB * SS / GQ, 512, 0, stream>>>(Qs, Kf, Vf, out);
}

// Round 7
// 209.878 us; speedup vs baseline: 1.0149x; 1.0149x over previous
//
#include <hip/hip_runtime.h>
#include <hip/hip_bf16.h>

#define BB 4
#define SS 2048
#define DIN 512
#define UU 64
#define WINR 32
#define LTOT 132064   // sum of per-anchor window lengths
#define GQ 16         // queries per attn block (16 waves x 1 query)
#define NWP 144       // max union key-window rows for GQ=16 (64+16+64)
#define KST 66        // ushort stride for K/V LDS rows (132 B -> conflict-free)

typedef __attribute__((ext_vector_type(8))) short short8;
typedef __attribute__((ext_vector_type(4))) float float4v;

static __device__ __forceinline__ ushort f2bf(float f) {
    union { __hip_bfloat16 h; ushort u; } c;
    c.h = __float2bfloat16(f);
    return c.u;
}
static __device__ __forceinline__ float bf2f(ushort u) {
    union { float f; uint v; } c;
    c.v = ((uint)u) << 16;
    return c.f;
}

// offsets[s] = sum_{t<s} (min(t+33,S) - max(t-32,0)), closed form (verified vs cumsum)
__device__ __forceinline__ int offs_of(int s) {
    int a = s < (SS - 33) ? s : (SS - 33);
    int m = (s - 33) > 0 ? (s - 33) : 0;
    return a * (a - 1) / 2 + 33 * a + (s - a) * SS - m * (m + 1) / 2;
}

// ---------------- Kernel 0: W (fp32, K-major [512][64]) -> Wt (bf16, N-major [3][64][512]) ----
__global__ __launch_bounds__(256) void prep_w(
    const float* __restrict__ Wq, const float* __restrict__ Wk, const float* __restrict__ Wv,
    ushort* __restrict__ Wt)
{
    __shared__ float T[64][65];
    const int mtx = blockIdx.x >> 3;   // 0..2
    const int kc  = blockIdx.x & 7;    // 0..7  (K chunk of 64)
    const float* W = (mtx == 0) ? Wq : ((mtx == 1) ? Wk : Wv);
    const int tid = threadIdx.x;
    for (int idx = tid; idx < 64 * 64; idx += 256) {
        const int k = idx >> 6, n = idx & 63;          // coalesced read over n
        T[n][k] = W[(size_t)(kc * 64 + k) * UU + n];
    }
    __syncthreads();
    for (int idx = tid; idx < 64 * 64; idx += 256) {
        const int n = idx >> 6, kl = idx & 63;
        Wt[(size_t)mtx * UU * DIN + (size_t)n * DIN + kc * 64 + kl] = f2bf(T[n][kl]);
    }
}

// ---------------- Kernel 1: QKV projection, MFMA 16x16x32, K-split across 4 waves ----------
// (round-5 verbatim, known-pass) grid = 3*512 blocks x 256 threads.
// Wave kq handles K range [kq*128, kq*128+128); partials reduced through LDS.
// A-fragments read directly from GLOBAL fp32 (16B-aligned), B from Wt (16B-aligned).
__global__ __launch_bounds__(256) void qkv_mfma(
    const float* __restrict__ query, const float* __restrict__ value,
    const ushort* __restrict__ Wt,
    const float* __restrict__ bq, const float* __restrict__ bk, const float* __restrict__ bv,
    float* __restrict__ Qs, ushort* __restrict__ Kf, ushort* __restrict__ Vf)
{
    __shared__ float red[4][16 * UU];   // 16 KB partials
    const int bid = blockIdx.x;
    const int mtx = bid >> 9;           // 0=Q 1=K 2=V
    const int rt  = bid & 511;
    const int tid = threadIdx.x;
    const int kq = tid >> 6;            // K-quarter
    const int lane = tid & 63;
    const int m16 = lane & 15, quad = lane >> 4;

    const float* X = (mtx == 0) ? query : value;
    const float* Xrow = X + (size_t)(rt * 16 + m16) * DIN + kq * 128 + quad * 8;
    const ushort* Wm = Wt + (size_t)mtx * UU * DIN + (size_t)m16 * DIN + kq * 128 + quad * 8;

    float4v acc[4];
#pragma unroll
    for (int nb = 0; nb < 4; ++nb) acc[nb] = (float4v){0.f, 0.f, 0.f, 0.f};

#pragma unroll
    for (int kk = 0; kk < 4; ++kk) {
        const float4 xa = *(const float4*)(Xrow + kk * 32);
        const float4 xb = *(const float4*)(Xrow + kk * 32 + 4);
        short8 a;
        a[0] = (short)f2bf(xa.x); a[1] = (short)f2bf(xa.y);
        a[2] = (short)f2bf(xa.z); a[3] = (short)f2bf(xa.w);
        a[4] = (short)f2bf(xb.x); a[5] = (short)f2bf(xb.y);
        a[6] = (short)f2bf(xb.z); a[7] = (short)f2bf(xb.w);
#pragma unroll
        for (int nb = 0; nb < 4; ++nb) {
            const short8 bfr = *(const short8*)(Wm + (size_t)nb * 16 * DIN + kk * 32);
            acc[nb] = __builtin_amdgcn_mfma_f32_16x16x32_bf16(a, bfr, acc[nb], 0, 0, 0);
        }
    }

    // C layout (16x16x32): col = lane&15 (within nb tile), row = quad*4 + reg
#pragma unroll
    for (int nb = 0; nb < 4; ++nb)
#pragma unroll
        for (int reg = 0; reg < 4; ++reg)
            red[kq][(quad * 4 + reg) * UU + nb * 16 + m16] = acc[nb][reg];
    __syncthreads();

    const float* bias = (mtx == 0) ? bq : ((mtx == 1) ? bk : bv);
#pragma unroll
    for (int i = 0; i < 4; ++i) {
        const int e = tid + 256 * i;
        const int col = e & 63, row = e >> 6;
        float s = red[0][e] + red[1][e] + red[2][e] + red[3][e] + bias[col];
        const size_t gi = (size_t)(rt * 16 + row) * UU + col;
        if (mtx == 0)      Qs[gi] = s * 0.125f;    // 1/sqrt(UNITS)
        else if (mtx == 1) Kf[gi] = f2bf(s);
        else               Vf[gi] = f2bf(s);
    }
}

// ---------------- Kernel 2: banded exp-scores + sliding-window weighted sums ----------
// 512 blocks x 1024 thr (16 waves); GQ=16 queries, one query per wave, full anchor range.
// 51.3 KB LDS -> 2 blocks/CU x 16 waves = 32 waves/CU (full occupancy).
// No softmax-max pass (|score| small; softmax shift-invariant).
__global__ __launch_bounds__(1024) void attn_kernel(
    const float* __restrict__ Qs, const ushort* __restrict__ Kf,
    const ushort* __restrict__ Vf, float* __restrict__ out)
{
    __shared__ ushort Kl[NWP * KST];     // 19,008 B
    __shared__ ushort Vl[NWP * KST];     // 19,008 B
    __shared__ float  ev[GQ][NWP];       //  9,216 B
    __shared__ float  qr[GQ][UU];        //  4,096 B   (51.3 KB total)

    const int blk = blockIdx.x;
    const int b = blk >> 7;              // 128 blocks per batch
    const int q0 = (blk & 127) << 4;
    const int tid = threadIdx.x;

    const int j0 = max(q0 - 2 * WINR, 0);
    const int j1 = min(q0 + GQ - 1 + 2 * WINR + 1, SS);
    const int nw = j1 - j0;

    if (tid < GQ * UU)
        qr[tid >> 6][tid & 63] = Qs[((size_t)b * SS + q0) * UU + tid];

    const uint* Kg = (const uint*)(Kf + ((size_t)b * SS + j0) * UU);
    const uint* Vg = (const uint*)(Vf + ((size_t)b * SS + j0) * UU);
    for (int idx = tid; idx < nw * 32; idx += 1024) {
        const int j = idx >> 5, d2 = idx & 31;
        ((uint*)(Kl + j * KST))[d2] = Kg[idx];
        ((uint*)(Vl + j * KST))[d2] = Vg[idx];
    }
    __syncthreads();

    // exp-scores for all 16 queries over the union band (Q pre-scaled by 1/8)
    for (int item = tid; item < GQ * NWP; item += 1024) {
        const int g = item / NWP, jj = item - g * NWP;
        float e = 0.f;
        if (jj < nw) {
            const uint* kr = (const uint*)(Kl + jj * KST);
            const float* q = qr[g];
            float dot = 0.f;
#pragma unroll
            for (int p = 0; p < UU / 2; ++p) {
                const uint kp = kr[p];
                dot = fmaf(q[2 * p],     bf2f((ushort)kp),         dot);
                dot = fmaf(q[2 * p + 1], bf2f((ushort)(kp >> 16)), dot);
            }
            e = __expf(dot);
        }
        ev[g][jj] = e;
    }
    __syncthreads();

    // sliding-window accumulation: wave w -> query qi = q0 + w, full anchor range
    const int w = tid >> 6, lane = tid & 63;
    const int qi = q0 + w;
    const int s_lo = max(qi - WINR, 0);
    const int s_hi = min(qi + WINR, SS - 1);
    int st = max(s_lo - WINR, 0);
    int en = min(s_lo + WINR + 1, SS);
    const float* evg = ev[w];

    float acc = 0.f, den = 0.f;
    for (int j = st; j < en; ++j) {
        const float e = evg[j - j0];
        acc = fmaf(e, bf2f(Vl[(j - j0) * KST + lane]), acc);
        den += e;
    }
    int off = offs_of(s_lo);
    float* outb = out + (size_t)b * LTOT * UU;
    for (int s = s_lo;; ++s) {
        outb[(size_t)(off + qi - st) * UU + lane] = acc * __builtin_amdgcn_rcpf(den);
        if (s == s_hi) break;
        off += en - st;
        if (en < SS) {                   // window end grows: add key j = en
            const float e = evg[en - j0];
            acc = fmaf(e, bf2f(Vl[(en - j0) * KST + lane]), acc);
            den += e;
            ++en;
        }
        if (s + 1 > WINR) {              // window start grows: remove key j = st
            const float e = evg[st - j0];
            acc = fmaf(-e, bf2f(Vl[(st - j0) * KST + lane]), acc);
            den -= e;
            ++st;
        }
    }
}

extern "C" void kernel_launch(void* const* d_in, const int* in_sizes, int n_in,
                              void* d_out, int out_size, void* d_ws, size_t ws_size,
                              hipStream_t stream) {
    const float* query = (const float*)d_in[0];
    const float* value = (const float*)d_in[1];
    const float* Wq = (const float*)d_in[2];
    const float* bq = (const float*)d_in[3];
    const float* Wk = (const float*)d_in[4];
    const float* bk = (const float*)d_in[5];
    const float* Wv = (const float*)d_in[6];
    const float* bv = (const float*)d_in[7];
    float* out = (float*)d_out;

    // ws: Qs fp32 (2 MB) + Kf bf16 (1 MB) + Vf bf16 (1 MB)
    float* Qs = (float*)d_ws;
    ushort* Kf = (ushort*)(Qs + (size_t)BB * SS * UU);
    ushort* Vf = Kf + (size_t)BB * SS * UU;
    // Wt (bf16 [3][64][512], 192 KB) in the TAIL of d_out: prep_w writes, qkv_mfma reads,
    // attn_kernel then overwrites every output row (stream-ordered, 16B-aligned).
    ushort* Wt = (ushort*)((float*)d_out + (size_t)out_size) - (size_t)3 * UU * DIN;

    prep_w<<<24, 256, 0, stream>>>(Wq, Wk, Wv, Wt);
    qkv_mfma<<<3 * 512, 256, 0, stream>>>(query, value, Wt, bq, bk, bv, Qs, Kf, Vf);
    attn_kernel<<<512, 1024, 0, stream>>>(Qs, Kf, Vf, out);
}